// Round 18
// baseline (361.513 us; speedup 1.0000x reference)
//
#include <hip/hip_runtime.h>
#include <hip/hip_bf16.h>
#include <stdint.h>
#include <math.h>

typedef __attribute__((ext_vector_type(8))) short bf16x8;
typedef __attribute__((ext_vector_type(4))) float f32x4;
typedef __attribute__((ext_vector_type(8))) unsigned short ushort8;
typedef __attribute__((ext_vector_type(4))) unsigned int uint4v;
typedef __attribute__((ext_vector_type(2))) unsigned int uint2v;

#define NTOK   9232      // 16*577 tokens per stream
#define MROWS  18464     // 2*NTOK
#define MPAD   18688     // 73*256
#define NPADV  640       // padded KV length for Vt rows
// Q prescale: 1/sqrt(64) * log2(e) so softmax uses raw 2^x
#define QSCALE 0.18033688011112042f

__device__ __forceinline__ uint16_t f2b(float f) {
  uint32_t u = __builtin_bit_cast(uint32_t, f);
  u += 0x7fffu + ((u >> 16) & 1u);
  return (uint16_t)(u >> 16);
}

__device__ __forceinline__ uint32_t packbf(float lo, float hi) {
  return (uint32_t)f2b(lo) | ((uint32_t)f2b(hi) << 16);
}

__device__ __forceinline__ f32x4 mfma16(bf16x8 a, bf16x8 b, f32x4 c) {
  return __builtin_amdgcn_mfma_f32_16x16x32_bf16(a, b, c, 0, 0, 0);
}

__device__ __forceinline__ void gl_lds16(const void* g, void* l) {
  __builtin_amdgcn_global_load_lds(
      (const __attribute__((address_space(1))) uint32_t*)g,
      (__attribute__((address_space(3))) uint32_t*)l, 16, 0, 0);
}

// ---------------------------------------------------------------- convert X
__global__ void convert_x_kernel(const float* __restrict__ x1,
                                 const float* __restrict__ x2,
                                 uint16_t* __restrict__ Xb) {
  const size_t stride = (size_t)gridDim.x * blockDim.x;
  const size_t total8 = (size_t)MPAD * 1024 / 8;
  for (size_t i = (size_t)blockIdx.x * blockDim.x + threadIdx.x; i < total8; i += stride) {
    const size_t e = i * 8;
    const size_t row = e >> 10;
    ushort8 ov;
    if (row < (size_t)MROWS) {
      const float* src = (row < (size_t)NTOK) ? (x1 + e) : (x2 + (e - (size_t)NTOK * 1024));
      float4 a = *(const float4*)(src);
      float4 b = *(const float4*)(src + 4);
      ov[0] = f2b(a.x); ov[1] = f2b(a.y); ov[2] = f2b(a.z); ov[3] = f2b(a.w);
      ov[4] = f2b(b.x); ov[5] = f2b(b.y); ov[6] = f2b(b.z); ov[7] = f2b(b.w);
    } else {
      ov = (ushort8)0;
    }
    *(ushort8*)(Xb + e) = ov;
  }
}

// ------------------------------------------------- transpose-convert weights
__global__ void transw_kernel(const float* __restrict__ in, uint16_t* __restrict__ out,
                              int R, int Cc) {
  __shared__ float t[32][33];
  const int r0 = blockIdx.x * 32, c0 = blockIdx.y * 32;
  const int tr = threadIdx.x >> 5, tc = threadIdx.x & 31;
#pragma unroll
  for (int i = 0; i < 4; ++i)
    t[tr + i * 8][tc] = in[(size_t)(r0 + tr + i * 8) * Cc + c0 + tc];
  __syncthreads();
#pragma unroll
  for (int i = 0; i < 4; ++i) {
    const int orow = c0 + tr + i * 8;
    out[(size_t)orow * R + r0 + tc] = f2b(t[tc][tr + i * 8]);
  }
}

// ----------------------------------------------- zero V-pad (replaces memset)
__global__ void zero_vpad_kernel(uint16_t* __restrict__ Vtb) {
  const int idx = blockIdx.x * 256 + threadIdx.x;   // 32768*8 chunks of 16B
  for (int i = idx; i < 32768 * 8; i += 256 * 256) {
    const int p = i >> 3;          // (bh,d) row
    const int ch = i & 7;          // 16B chunk within 128B pad
    *(ushort8*)(Vtb + (size_t)p * NPADV + 576 + ch * 8) = (ushort8)0;
  }
}

// ===== 256x256 tile, BK=32, 8-wave, RING-2, 1-barrier GEMM core ============
// (R17-verified: 64KB LDS, (512,1), 128 VGPR no spill, 145.8us on qkv.)
#define G256_SETUP                                                             \
  const int srow = tt >> 2;       /* 0..127 */                                 \
  const int schunk = tt & 3;      /* 16B chunk in 64B row */                   \
  const int swc = schunk ^ ((srow >> 1) & 3);                                  \
  const int crs = (c >> 1) & 3;                                                \
  char* aL = (char*)As3;                                                       \
  char* bL = (char*)Bs3;                                                       \
  auto SA = [&](int buf, int t) {                                              \
    _Pragma("unroll")                                                          \
    for (int i = 0; i < 2; ++i) {                                              \
      const int row = i * 128 + srow;                                          \
      gl_lds16(aG + (size_t)row * 2048 + t * 64 + (swc << 4),                  \
               aL + buf * 16384 + row * 64 + (schunk << 4));                   \
    }                                                                          \
  };                                                                           \
  auto SB = [&](int buf, int t) {                                              \
    _Pragma("unroll")                                                          \
    for (int i = 0; i < 2; ++i) {                                              \
      const int row = i * 128 + srow;                                          \
      gl_lds16(bG + (size_t)row * 2048 + t * 64 + (swc << 4),                  \
               bL + buf * 16384 + row * 64 + (schunk << 4));                   \
    }                                                                          \
  };                                                                           \
  auto LDA = [&](int buf, int mi) -> bf16x8 {                                  \
    const int r = wm * 128 + mi * 16 + c;                                      \
    return *(const bf16x8*)(aL + buf * 16384 + r * 64 + ((g ^ crs) << 4));     \
  };                                                                           \
  auto LDB = [&](int buf, int ni) -> bf16x8 {                                  \
    const int r = wn * 64 + ni * 16 + c;                                       \
    return *(const bf16x8*)(bL + buf * 16384 + r * 64 + ((g ^ crs) << 4));     \
  };

#define G256_MFMA_BLOCK(BR)                                                    \
  {                                                                            \
    bf16x8 b0 = LDB(BR, 0), b1 = LDB(BR, 1);                                   \
    bf16x8 b2 = LDB(BR, 2), b3 = LDB(BR, 3);                                   \
    __builtin_amdgcn_s_setprio(1);                                             \
    _Pragma("unroll")                                                          \
    for (int mi = 0; mi < 8; ++mi) {                                           \
      const bf16x8 a0 = LDA(BR, mi);                                           \
      acc[mi][0] = mfma16(a0, b0, acc[mi][0]);                                 \
      acc[mi][1] = mfma16(a0, b1, acc[mi][1]);                                 \
      acc[mi][2] = mfma16(a0, b2, acc[mi][2]);                                 \
      acc[mi][3] = mfma16(a0, b3, acc[mi][3]);                                 \
    }                                                                          \
    __builtin_amdgcn_s_setprio(0);                                             \
  }

// iter T reading literal buf BR; stage T+1 into BR^1 after the barrier.
#define G256R2_ITER(T, BR)                                                     \
  {                                                                            \
    asm volatile("s_waitcnt vmcnt(0)" ::: "memory");                           \
    __builtin_amdgcn_s_barrier();                                              \
    __builtin_amdgcn_sched_barrier(0);                                         \
    if ((T) < 31) { SA((BR) ^ 1, (T) + 1); SB((BR) ^ 1, (T) + 1); }            \
    G256_MFMA_BLOCK(BR)                                                        \
  }

#define G256_KLOOP                                                             \
  G256_SETUP                                                                   \
  SA(0, 0); SB(0, 0);                                                          \
  for (int j2 = 0; j2 < 16; ++j2) {                                            \
    G256R2_ITER(2 * j2, 0)                                                     \
    G256R2_ITER(2 * j2 + 1, 1)                                                 \
  }

// ---------------------------------------------------------------- QKV GEMM
// grid 876 = 73 bm x 12 bn; bijective XCD swizzle + 3x4 supertile raster.
// Chunked LDS-staged epilogue (R15/R17-verified).
__global__ __launch_bounds__(512, 1) void gemm_qkv_kernel(
    const uint16_t* __restrict__ A, const uint16_t* __restrict__ Bt,
    uint16_t* __restrict__ Qb, uint16_t* __restrict__ Kb, uint16_t* __restrict__ Vtb) {
  __shared__ __align__(128) char smem[65536];
  uint16_t* As3 = (uint16_t*)smem;               // 2 bufs x 16KB
  uint16_t* Bs3 = (uint16_t*)(smem + 32768);     // 2 bufs x 16KB
  const int tt = threadIdx.x;
  const int w = tt >> 6, l = tt & 63;
  const int c = l & 15, g = l >> 4;
  const int wm = w >> 2, wn = w & 3;
  const int orig = blockIdx.x;
  const int xcd = orig & 7, sub8 = orig >> 3;
  const int work = (xcd < 4 ? xcd * 110 : 440 + (xcd - 4) * 109) + sub8;
  int bm, bn;
  {
    const int stripe = work / 36;
    if (stripe >= 24) { bm = 72; bn = work - 864; }
    else {
      const int r2 = work % 36;
      const int bg = r2 / 12, r3 = r2 % 12;
      bm = stripe * 3 + r3 % 3;
      bn = bg * 4 + r3 / 3;
    }
  }
  f32x4 acc[8][4] = {};
  const char* aG = (const char*)(A + (size_t)bm * 256 * 1024);
  const char* bG = (const char*)(Bt + (size_t)bn * 256 * 1024);

  G256_KLOOP

  // ================= LDS-staged epilogue (chunked, R15/R17-verified) =======
  const int sArea = bn >> 2;  // 0:Q 1:K 2:V
  __syncthreads();            // all K-loop LDS reads done; smem reusable
  if (sArea <= 1) {
    uint16_t* outb = (sArea == 0) ? Qb : Kb;
    const float scale = (sArea == 0) ? QSCALE : 1.0f;
#pragma unroll
    for (int q = 0; q < 4; ++q) {
      if (wm == (q >> 1)) {
        char* wbase = smem + (g * 4) * 544 + (wn * 64 + c) * 2;
#pragma unroll
        for (int mi2 = 0; mi2 < 4; ++mi2) {
          const int mi = (q & 1) * 4 + mi2;
#pragma unroll
          for (int r = 0; r < 4; ++r)
#pragma unroll
            for (int ni = 0; ni < 4; ++ni)
              *(uint16_t*)(wbase + mi2 * 8704 + r * 544 + ni * 32) =
                  f2b(acc[mi][ni][r] * scale);
        }
      }
      __syncthreads();
      {
        const int row = tt >> 3, hp = tt & 7;
        const int R = bm * 256 + q * 64 + row;
        if (R < MROWS) {
          const int src = (R >= NTOK) ? 1 : 0;
          const int rr = R - src * NTOK;
          const int bb = rr / 577;
          const int nn = rr - bb * 577;
          const size_t base0 =
              ((((size_t)src * 16 + bb) * 16 + (bn & 3) * 4) * 577 + nn) * 64;
          const char* rbase = smem + row * 544;
#pragma unroll
          for (int j = 0; j < 4; ++j) {
            const int ch = hp + j * 8;
            const int hh2 = ch >> 3;
            const int dd = (ch & 7) * 8;
            const uint4v v = *(const uint4v*)(rbase + ch * 16);
            *(uint4v*)(outb + base0 + (size_t)hh2 * 577 * 64 + dd) = v;
          }
        }
      }
      __syncthreads();
    }
  } else {
#pragma unroll
    for (int half = 0; half < 2; ++half) {
#pragma unroll
      for (int hv = 0; hv < 2; ++hv) {
        if (wm == half && (wn >> 1) == hv) {
          char* wbase = smem + ((wn & 1) * 64 + c) * 272 + g * 8;
#pragma unroll
          for (int mi = 0; mi < 8; ++mi)
#pragma unroll
            for (int ni = 0; ni < 4; ++ni) {
              const uint2v pw = {packbf(acc[mi][ni][0], acc[mi][ni][1]),
                                 packbf(acc[mi][ni][2], acc[mi][ni][3])};
              *(uint2v*)(wbase + ni * 4352 + mi * 32) = pw;
            }
        }
        __syncthreads();
        {
          const int col = tt >> 2, s = tt & 3;
          const int C = bn * 256 + hv * 128 + col;
          const int hh2 = (C >> 6) & 15;
          const int dd = C & 63;
          const char* rbase = smem + col * 272 + s * 64;
#pragma unroll
          for (int j = 0; j < 4; ++j) {
            const int R0 = bm * 256 + half * 128 + s * 32 + j * 8;
            if (R0 >= MROWS) continue;
            const int src0 = (R0 >= NTOK) ? 1 : 0;
            const int rr0 = R0 - src0 * NTOK;
            const int bb0 = rr0 / 577;
            const int nn0 = rr0 - bb0 * 577;
            const uint4v v = *(const uint4v*)(rbase + j * 16);
            const uint16_t* pv = (const uint16_t*)&v;
            const bool fast = (R0 + 7 < MROWS) && (nn0 + 8 <= 577) &&
                              (((R0 + 7) >= NTOK ? 1 : 0) == src0);
            if (fast) {
              uint16_t* dst =
                  Vtb + ((((size_t)src0 * 16 + bb0) * 16 + hh2) * 64 + dd) * NPADV + nn0;
#pragma unroll
              for (int e = 0; e < 8; ++e) dst[e] = pv[e];
            } else {
#pragma unroll
              for (int e = 0; e < 8; ++e) {
                const int R = R0 + e;
                if (R >= MROWS) break;
                const int sx = (R >= NTOK) ? 1 : 0;
                const int rr = R - sx * NTOK;
                const int b2 = rr / 577;
                const int n2 = rr - b2 * 577;
                Vtb[((((size_t)sx * 16 + b2) * 16 + hh2) * 64 + dd) * NPADV + n2] = pv[e];
              }
            }
          }
        }
        __syncthreads();
      }
    }
  }
}

// ---------------------------------------------------------------- Proj GEMM
// R18: 256^2 ring-2 core (R17-verified on qkv). Grid 292 = 73 bm x 4 bn;
// at 64KB LDS / 2-blk-capacity all 292 blocks co-resident -> no tail round.
// Bijective XCD split (q=36, r=4); stripe-of-3 raster (A 1.5MB + B 2MB < L2).
__global__ __launch_bounds__(512, 1) void gemm_proj_kernel(
    const uint16_t* __restrict__ A, const uint16_t* __restrict__ Bt,
    const float* __restrict__ bias, float* __restrict__ out) {
  __shared__ __align__(128) char smem[65536];
  uint16_t* As3 = (uint16_t*)smem;               // 2 bufs x 16KB
  uint16_t* Bs3 = (uint16_t*)(smem + 32768);     // 2 bufs x 16KB
  const int tt = threadIdx.x;
  const int w = tt >> 6, l = tt & 63;
  const int c = l & 15, g = l >> 4;
  const int wm = w >> 2, wn = w & 3;
  const int orig = blockIdx.x;
  const int xcd = orig & 7, sub8 = orig >> 3;
  const int work = (xcd < 4 ? xcd * 37 : 148 + (xcd - 4) * 36) + sub8;
  int bm, bn;
  {
    const int stripe = work / 12;
    if (stripe >= 24) { bm = 72; bn = work - 288; }
    else { const int r3 = work % 12; bm = stripe * 3 + r3 % 3; bn = r3 / 3; }
  }
  f32x4 acc[8][4] = {};
  const char* aG = (const char*)(A + (size_t)bm * 256 * 1024);
  const char* bG = (const char*)(Bt + (size_t)bn * 256 * 1024);

  G256_KLOOP

#pragma unroll
  for (int mi = 0; mi < 8; ++mi) {
#pragma unroll
    for (int r = 0; r < 4; ++r) {
      const int R = bm * 256 + wm * 128 + mi * 16 + g * 4 + r;
      if (R >= MROWS) continue;
#pragma unroll
      for (int ni = 0; ni < 4; ++ni) {
        const int C = bn * 256 + wn * 64 + ni * 16 + c;
        out[(size_t)R * 1024 + C] = acc[mi][ni][r] + bias[C];
      }
    }
  }
}

// ---------------------------------------------------------------- attention
// Cooperative flash attn, 16x16x32 MFMA (R5-verified layouts) + T13
// defer-max (R16-verified) + T5 setprio around MFMA clusters (R18).
#define KVB 64
#define ATT_NT 10
__global__ __launch_bounds__(256, 2) void attn_kernel(
    const uint16_t* __restrict__ Qb, const uint16_t* __restrict__ Kb,
    const uint16_t* __restrict__ Vtb, uint16_t* __restrict__ O) {
  __shared__ __align__(128) char smem[73728];  // Ks[2][8K] | Vs[2][8K] | P[4][10K]
  const int tid = threadIdx.x;
  const int w = tid >> 6, l = tid & 63;
  const int c = l & 15, g = l >> 4;
  const int bid = blockIdx.x;
  const int qc = bid & 1;
  const int p = bid >> 1;
  const int h = p & 15, b = (p >> 4) & 15, o = p >> 8;
  const int kvsrc = (h < 10) ? o : (1 - o);
  const uint16_t* qp = Qb + (((size_t)o * 16 + b) * 16 + h) * 577 * 64;
  const uint16_t* kp = Kb + (((size_t)kvsrc * 16 + b) * 16 + h) * 577 * 64;
  const uint16_t* vp = Vtb + (((size_t)kvsrc * 16 + b) * 16 + h) * 64 * NPADV;

  const int qbase = qc * 320 + w * 80;

  const int sub = l >> 3;
  const int colEl = (((l & 7) ^ sub) << 3);  // element offset in row
  char* KsA = smem;
  char* VsA = smem + 16384;
  char* Pb  = smem + 32768 + w * 10240;      // per-wave P / epilogue buffer
  const int rs = (c & 7) << 4;               // swizzle for LDS rows ≡ c (mod 8)

  bf16x8 Qf[5][2];
#pragma unroll
  for (int qt = 0; qt < 5; ++qt) {
    const int qrow = min(qbase + qt * 16 + c, 576);
    const uint16_t* qr = qp + (size_t)qrow * 64 + g * 8;
    Qf[qt][0] = *(const bf16x8*)(qr);
    Qf[qt][1] = *(const bf16x8*)(qr + 32);
  }

  f32x4 acc[4][5] = {};  // [dt][qt]
  float m_run[5] = {-3.0e38f, -3.0e38f, -3.0e38f, -3.0e38f, -3.0e38f};
  float l_run[5] = {0.f, 0.f, 0.f, 0.f, 0.f};

  auto STAGE = [&](int buf, int kv0) {
#pragma unroll
    for (int i = 0; i < 2; ++i) {
      const int j = w * 2 + i;
      const int row = j * 8 + sub;
      const int gk = min(kv0 + row, 576);
      gl_lds16(kp + (size_t)gk * 64 + colEl, KsA + buf * 8192 + j * 1024 + l * 16);
      gl_lds16(vp + (size_t)row * NPADV + kv0 + colEl, VsA + buf * 8192 + j * 1024 + l * 16);
    }
  };

  STAGE(0, 0);
  __syncthreads();

  for (int t = 0; t < ATT_NT; ++t) {
    if (t < ATT_NT - 1) STAGE((t + 1) & 1, (t + 1) * KVB);
    {
      const char* Kt = KsA + (t & 1) * 8192;
      const char* Vt = VsA + (t & 1) * 8192;
      bf16x8 Kf[4][2];
#pragma unroll
      for (int kt = 0; kt < 4; ++kt) {
        const char* kr = Kt + (kt * 16 + c) * 128;
        Kf[kt][0] = *(const bf16x8*)(kr + ((g * 16) ^ rs));
        Kf[kt][1] = *(const bf16x8*)(kr + ((64 + g * 16) ^ rs));
      }
      float alpha_[5];
#pragma unroll
      for (int qt = 0; qt < 5; ++qt) {
        f32x4 s[4];
        __builtin_amdgcn_s_setprio(1);
#pragma unroll
        for (int kt = 0; kt < 4; ++kt) {
          f32x4 z = {0.f, 0.f, 0.f, 0.f};
          z = mfma16(Kf[kt][0], Qf[qt][0], z);
          z = mfma16(Kf[kt][1], Qf[qt][1], z);
          s[kt] = z;
        }
        __builtin_amdgcn_s_setprio(0);
        if (t == ATT_NT - 1) {
#pragma unroll
          for (int kt = 0; kt < 4; ++kt)
#pragma unroll
            for (int r = 0; r < 4; ++r) {
              if (kt == 0 && r == 0) { if (g > 0) s[kt][r] = -3.0e38f; }
              else s[kt][r] = -3.0e38f;
            }
        }
        float mt = s[0][0];
#pragma unroll
        for (int kt = 0; kt < 4; ++kt)
#pragma unroll
          for (int r = 0; r < 4; ++r) mt = fmaxf(mt, s[kt][r]);
        mt = fmaxf(mt, __shfl_xor(mt, 16));
        mt = fmaxf(mt, __shfl_xor(mt, 32));
        // T13 defer-max: rescale only when tile max exceeds running max by >8.
        float al;
        if (mt > m_run[qt] + 8.0f) {
          al = exp2f(m_run[qt] - mt);
          m_run[qt] = mt;
        } else {
          al = 1.0f;
        }
        alpha_[qt] = al;
        const float mcur = m_run[qt];
        float lt = 0.f;
#pragma unroll
        for (int kt = 0; kt < 4; ++kt)
#pragma unroll
          for (int r = 0; r < 4; ++r) {
            const float pv = exp2f(s[kt][r] - mcur);
            s[kt][r] = pv;
            lt += pv;
          }
        lt += __shfl_xor(lt, 16);
        lt += __shfl_xor(lt, 32);
        l_run[qt] = l_run[qt] * al + lt;
        const int rowOff = (qt * 16 + c) * 128;
#pragma unroll
        for (int kt = 0; kt < 4; ++kt) {
          const uint2v pw = {packbf(s[kt][0], s[kt][1]), packbf(s[kt][2], s[kt][3])};
          *(uint2v*)(Pb + rowOff + ((kt * 32 + g * 8) ^ rs)) = pw;
        }
      }
#pragma unroll
      for (int qt = 0; qt < 5; ++qt) {
        if (alpha_[qt] != 1.0f) {
#pragma unroll
          for (int dt = 0; dt < 4; ++dt)
#pragma unroll
            for (int r = 0; r < 4; ++r) acc[dt][qt][r] *= alpha_[qt];
        }
      }
      bf16x8 pf[5][2];
#pragma unroll
      for (int qt = 0; qt < 5; ++qt) {
        const char* pr = Pb + (qt * 16 + c) * 128;
        pf[qt][0] = *(const bf16x8*)(pr + ((g * 16) ^ rs));
        pf[qt][1] = *(const bf16x8*)(pr + ((64 + g * 16) ^ rs));
      }
      __builtin_amdgcn_s_setprio(1);
#pragma unroll
      for (int dt = 0; dt < 4; ++dt) {
        const char* vr = Vt + (dt * 16 + c) * 128;
        const bf16x8 v0 = *(const bf16x8*)(vr + ((g * 16) ^ rs));
        const bf16x8 v1 = *(const bf16x8*)(vr + ((64 + g * 16) ^ rs));
#pragma unroll
        for (int qt = 0; qt < 5; ++qt) {
          acc[dt][qt] = mfma16(v0, pf[qt][0], acc[dt][qt]);
          acc[dt][qt] = mfma16(v1, pf[qt][1], acc[dt][qt]);
        }
      }
      __builtin_amdgcn_s_setprio(0);
    }
    __syncthreads();
  }

  {
#pragma unroll
    for (int qt = 0; qt < 5; ++qt) {
      const float inv = 1.0f / l_run[qt];
      const int rowOff = (qt * 16 + c) * 128;
#pragma unroll
      for (int dt = 0; dt < 4; ++dt) {
        const uint2v pw = {packbf(acc[dt][qt][0] * inv, acc[dt][qt][1] * inv),
                           packbf(acc[dt][qt][2] * inv, acc[dt][qt][3] * inv)};
        *(uint2v*)(Pb + rowOff + ((dt * 32 + g * 8) ^ rs)) = pw;
      }
    }
    const size_t obase = ((size_t)o * NTOK + (size_t)b * 577) * 1024 + h * 64;
#pragma unroll
    for (int pass = 0; pass < 10; ++pass) {
      const int row = pass * 8 + (l >> 3);
      const int tok = qbase + row;
      const uint4v vv = *(const uint4v*)(Pb + row * 128 + (((l & 7) * 16) ^ ((row & 7) << 4)));
      if (tok <= 576)
        *(uint4v*)(O + obase + (size_t)tok * 1024 + (l & 7) * 8) = vv;
    }
  }
}

// ---------------------------------------------------------------- launch
extern "C" void kernel_launch(void* const* d_in, const int* in_sizes, int n_in,
                              void* d_out, int out_size, void* d_ws, size_t ws_size,
                              hipStream_t stream) {
  (void)in_sizes; (void)n_in; (void)out_size; (void)ws_size;
  const float* x1    = (const float*)d_in[0];
  const float* x2    = (const float*)d_in[1];
  const float* Wqkv  = (const float*)d_in[2];
  const float* Wproj = (const float*)d_in[3];
  const float* bproj = (const float*)d_in[4];
  float* out = (float*)d_out;

  char* ws = (char*)d_ws;
  size_t off = 0;
  auto alloc = [&](size_t bytes) -> char* {
    char* p = ws + off;
    off += (bytes + 255) & ~(size_t)255;
    return p;
  };
  uint16_t* Xb     = (uint16_t*)alloc((size_t)MPAD * 1024 * 2);      // also AttOut
  uint16_t* Wqkvt  = (uint16_t*)alloc((size_t)3072 * 1024 * 2);
  uint16_t* Wprojt = (uint16_t*)alloc((size_t)1024 * 1024 * 2);
  uint16_t* Qb     = (uint16_t*)alloc((size_t)512 * 577 * 64 * 2);
  uint16_t* Kb     = (uint16_t*)alloc((size_t)512 * 577 * 64 * 2);
  uint16_t* Vtb    = (uint16_t*)alloc((size_t)512 * 64 * NPADV * 2);

  zero_vpad_kernel<<<256, 256, 0, stream>>>(Vtb);
  convert_x_kernel<<<2048, 256, 0, stream>>>(x1, x2, Xb);
  transw_kernel<<<dim3(32, 96), 256, 0, stream>>>(Wqkv, Wqkvt, 1024, 3072);
  transw_kernel<<<dim3(32, 32), 256, 0, stream>>>(Wproj, Wprojt, 1024, 1024);
  gemm_qkv_kernel<<<876, 512, 0, stream>>>(Xb, Wqkvt, Qb, Kb, Vtb);
  attn_kernel<<<1024, 256, 0, stream>>>(Qb, Kb, Vtb, Xb /* AttOut */);
  gemm_proj_kernel<<<292, 512, 0, stream>>>(Xb, Wprojt, bproj, out);
}

// Round 19
// 352.673 us; speedup vs baseline: 1.0251x; 1.0251x over previous
//
#include <hip/hip_runtime.h>
#include <hip/hip_bf16.h>
#include <stdint.h>
#include <math.h>

typedef __attribute__((ext_vector_type(8))) short bf16x8;
typedef __attribute__((ext_vector_type(4))) float f32x4;
typedef __attribute__((ext_vector_type(8))) unsigned short ushort8;
typedef __attribute__((ext_vector_type(4))) unsigned int uint4v;
typedef __attribute__((ext_vector_type(2))) unsigned int uint2v;

#define NTOK   9232      // 16*577 tokens per stream
#define MROWS  18464     // 2*NTOK
#define MPAD   18688     // 73*256 (also 146*128 for proj tiles)
#define NPADV  640       // padded KV length for Vt rows
// Q prescale: 1/sqrt(64) * log2(e) so softmax uses raw 2^x
#define QSCALE 0.18033688011112042f

__device__ __forceinline__ uint16_t f2b(float f) {
  uint32_t u = __builtin_bit_cast(uint32_t, f);
  u += 0x7fffu + ((u >> 16) & 1u);
  return (uint16_t)(u >> 16);
}

__device__ __forceinline__ uint32_t packbf(float lo, float hi) {
  return (uint32_t)f2b(lo) | ((uint32_t)f2b(hi) << 16);
}

__device__ __forceinline__ f32x4 mfma16(bf16x8 a, bf16x8 b, f32x4 c) {
  return __builtin_amdgcn_mfma_f32_16x16x32_bf16(a, b, c, 0, 0, 0);
}

__device__ __forceinline__ void gl_lds16(const void* g, void* l) {
  __builtin_amdgcn_global_load_lds(
      (const __attribute__((address_space(1))) uint32_t*)g,
      (__attribute__((address_space(3))) uint32_t*)l, 16, 0, 0);
}

// ---------------------------------------------------------------- convert X
__global__ void convert_x_kernel(const float* __restrict__ x1,
                                 const float* __restrict__ x2,
                                 uint16_t* __restrict__ Xb) {
  const size_t stride = (size_t)gridDim.x * blockDim.x;
  const size_t total8 = (size_t)MPAD * 1024 / 8;
  for (size_t i = (size_t)blockIdx.x * blockDim.x + threadIdx.x; i < total8; i += stride) {
    const size_t e = i * 8;
    const size_t row = e >> 10;
    ushort8 ov;
    if (row < (size_t)MROWS) {
      const float* src = (row < (size_t)NTOK) ? (x1 + e) : (x2 + (e - (size_t)NTOK * 1024));
      float4 a = *(const float4*)(src);
      float4 b = *(const float4*)(src + 4);
      ov[0] = f2b(a.x); ov[1] = f2b(a.y); ov[2] = f2b(a.z); ov[3] = f2b(a.w);
      ov[4] = f2b(b.x); ov[5] = f2b(b.y); ov[6] = f2b(b.z); ov[7] = f2b(b.w);
    } else {
      ov = (ushort8)0;
    }
    *(ushort8*)(Xb + e) = ov;
  }
}

// ------------------------------------------------- transpose-convert weights
__global__ void transw_kernel(const float* __restrict__ in, uint16_t* __restrict__ out,
                              int R, int Cc) {
  __shared__ float t[32][33];
  const int r0 = blockIdx.x * 32, c0 = blockIdx.y * 32;
  const int tr = threadIdx.x >> 5, tc = threadIdx.x & 31;
#pragma unroll
  for (int i = 0; i < 4; ++i)
    t[tr + i * 8][tc] = in[(size_t)(r0 + tr + i * 8) * Cc + c0 + tc];
  __syncthreads();
#pragma unroll
  for (int i = 0; i < 4; ++i) {
    const int orow = c0 + tr + i * 8;
    out[(size_t)orow * R + r0 + tc] = f2b(t[tc][tr + i * 8]);
  }
}

// ----------------------------------------------- zero V-pad (replaces memset)
__global__ void zero_vpad_kernel(uint16_t* __restrict__ Vtb) {
  const int idx = blockIdx.x * 256 + threadIdx.x;   // 32768*8 chunks of 16B
  for (int i = idx; i < 32768 * 8; i += 256 * 256) {
    const int p = i >> 3;          // (bh,d) row
    const int ch = i & 7;          // 16B chunk within 128B pad
    *(ushort8*)(Vtb + (size_t)p * NPADV + 576 + ch * 8) = (ushort8)0;
  }
}

// ===== 256x256 tile, BK=32, 8-wave, RING-2, 1-barrier GEMM core ============
// (R17-verified: 64KB LDS, (512,1), 128 VGPR no spill, 145.8us on qkv.
//  NOTE: HW refuses 2 blocks/CU at 8 waves x 128 VGPR -> 256^2 tiles must
//  have grid >= ~256*k with small tail; qkv's 876 is fine, proj's 292 is NOT
//  (R18 regression) -> proj stays on the 128^2 ring-3 core.)
#define G256_SETUP                                                             \
  const int srow = tt >> 2;       /* 0..127 */                                 \
  const int schunk = tt & 3;      /* 16B chunk in 64B row */                   \
  const int swc = schunk ^ ((srow >> 1) & 3);                                  \
  const int crs = (c >> 1) & 3;                                                \
  char* aL = (char*)As3;                                                       \
  char* bL = (char*)Bs3;                                                       \
  auto SA = [&](int buf, int t) {                                              \
    _Pragma("unroll")                                                          \
    for (int i = 0; i < 2; ++i) {                                              \
      const int row = i * 128 + srow;                                          \
      gl_lds16(aG + (size_t)row * 2048 + t * 64 + (swc << 4),                  \
               aL + buf * 16384 + row * 64 + (schunk << 4));                   \
    }                                                                          \
  };                                                                           \
  auto SB = [&](int buf, int t) {                                              \
    _Pragma("unroll")                                                          \
    for (int i = 0; i < 2; ++i) {                                              \
      const int row = i * 128 + srow;                                          \
      gl_lds16(bG + (size_t)row * 2048 + t * 64 + (swc << 4),                  \
               bL + buf * 16384 + row * 64 + (schunk << 4));                   \
    }                                                                          \
  };                                                                           \
  auto LDA = [&](int buf, int mi) -> bf16x8 {                                  \
    const int r = wm * 128 + mi * 16 + c;                                      \
    return *(const bf16x8*)(aL + buf * 16384 + r * 64 + ((g ^ crs) << 4));     \
  };                                                                           \
  auto LDB = [&](int buf, int ni) -> bf16x8 {                                  \
    const int r = wn * 64 + ni * 16 + c;                                       \
    return *(const bf16x8*)(bL + buf * 16384 + r * 64 + ((g ^ crs) << 4));     \
  };

#define G256_MFMA_BLOCK(BR)                                                    \
  {                                                                            \
    bf16x8 b0 = LDB(BR, 0), b1 = LDB(BR, 1);                                   \
    bf16x8 b2 = LDB(BR, 2), b3 = LDB(BR, 3);                                   \
    __builtin_amdgcn_s_setprio(1);                                             \
    _Pragma("unroll")                                                          \
    for (int mi = 0; mi < 8; ++mi) {                                           \
      const bf16x8 a0 = LDA(BR, mi);                                           \
      acc[mi][0] = mfma16(a0, b0, acc[mi][0]);                                 \
      acc[mi][1] = mfma16(a0, b1, acc[mi][1]);                                 \
      acc[mi][2] = mfma16(a0, b2, acc[mi][2]);                                 \
      acc[mi][3] = mfma16(a0, b3, acc[mi][3]);                                 \
    }                                                                          \
    __builtin_amdgcn_s_setprio(0);                                             \
  }

// iter T reading literal buf BR; stage T+1 into BR^1 after the barrier.
#define G256R2_ITER(T, BR)                                                     \
  {                                                                            \
    asm volatile("s_waitcnt vmcnt(0)" ::: "memory");                           \
    __builtin_amdgcn_s_barrier();                                              \
    __builtin_amdgcn_sched_barrier(0);                                         \
    if ((T) < 31) { SA((BR) ^ 1, (T) + 1); SB((BR) ^ 1, (T) + 1); }            \
    G256_MFMA_BLOCK(BR)                                                        \
  }

#define G256_KLOOP                                                             \
  G256_SETUP                                                                   \
  SA(0, 0); SB(0, 0);                                                          \
  for (int j2 = 0; j2 < 16; ++j2) {                                            \
    G256R2_ITER(2 * j2, 0)                                                     \
    G256R2_ITER(2 * j2 + 1, 1)                                                 \
  }

// ---------------------------------------------------------------- QKV GEMM
// grid 876 = 73 bm x 12 bn; bijective XCD swizzle + 3x4 supertile raster.
// Chunked LDS-staged epilogue (R15/R17-verified).
__global__ __launch_bounds__(512, 1) void gemm_qkv_kernel(
    const uint16_t* __restrict__ A, const uint16_t* __restrict__ Bt,
    uint16_t* __restrict__ Qb, uint16_t* __restrict__ Kb, uint16_t* __restrict__ Vtb) {
  __shared__ __align__(128) char smem[65536];
  uint16_t* As3 = (uint16_t*)smem;               // 2 bufs x 16KB
  uint16_t* Bs3 = (uint16_t*)(smem + 32768);     // 2 bufs x 16KB
  const int tt = threadIdx.x;
  const int w = tt >> 6, l = tt & 63;
  const int c = l & 15, g = l >> 4;
  const int wm = w >> 2, wn = w & 3;
  const int orig = blockIdx.x;
  const int xcd = orig & 7, sub8 = orig >> 3;
  const int work = (xcd < 4 ? xcd * 110 : 440 + (xcd - 4) * 109) + sub8;
  int bm, bn;
  {
    const int stripe = work / 36;
    if (stripe >= 24) { bm = 72; bn = work - 864; }
    else {
      const int r2 = work % 36;
      const int bg = r2 / 12, r3 = r2 % 12;
      bm = stripe * 3 + r3 % 3;
      bn = bg * 4 + r3 / 3;
    }
  }
  f32x4 acc[8][4] = {};
  const char* aG = (const char*)(A + (size_t)bm * 256 * 1024);
  const char* bG = (const char*)(Bt + (size_t)bn * 256 * 1024);

  G256_KLOOP

  // ================= LDS-staged epilogue (chunked, R15/R17-verified) =======
  const int sArea = bn >> 2;  // 0:Q 1:K 2:V
  __syncthreads();            // all K-loop LDS reads done; smem reusable
  if (sArea <= 1) {
    uint16_t* outb = (sArea == 0) ? Qb : Kb;
    const float scale = (sArea == 0) ? QSCALE : 1.0f;
#pragma unroll
    for (int q = 0; q < 4; ++q) {
      if (wm == (q >> 1)) {
        char* wbase = smem + (g * 4) * 544 + (wn * 64 + c) * 2;
#pragma unroll
        for (int mi2 = 0; mi2 < 4; ++mi2) {
          const int mi = (q & 1) * 4 + mi2;
#pragma unroll
          for (int r = 0; r < 4; ++r)
#pragma unroll
            for (int ni = 0; ni < 4; ++ni)
              *(uint16_t*)(wbase + mi2 * 8704 + r * 544 + ni * 32) =
                  f2b(acc[mi][ni][r] * scale);
        }
      }
      __syncthreads();
      {
        const int row = tt >> 3, hp = tt & 7;
        const int R = bm * 256 + q * 64 + row;
        if (R < MROWS) {
          const int src = (R >= NTOK) ? 1 : 0;
          const int rr = R - src * NTOK;
          const int bb = rr / 577;
          const int nn = rr - bb * 577;
          const size_t base0 =
              ((((size_t)src * 16 + bb) * 16 + (bn & 3) * 4) * 577 + nn) * 64;
          const char* rbase = smem + row * 544;
#pragma unroll
          for (int j = 0; j < 4; ++j) {
            const int ch = hp + j * 8;
            const int hh2 = ch >> 3;
            const int dd = (ch & 7) * 8;
            const uint4v v = *(const uint4v*)(rbase + ch * 16);
            *(uint4v*)(outb + base0 + (size_t)hh2 * 577 * 64 + dd) = v;
          }
        }
      }
      __syncthreads();
    }
  } else {
#pragma unroll
    for (int half = 0; half < 2; ++half) {
#pragma unroll
      for (int hv = 0; hv < 2; ++hv) {
        if (wm == half && (wn >> 1) == hv) {
          char* wbase = smem + ((wn & 1) * 64 + c) * 272 + g * 8;
#pragma unroll
          for (int mi = 0; mi < 8; ++mi)
#pragma unroll
            for (int ni = 0; ni < 4; ++ni) {
              const uint2v pw = {packbf(acc[mi][ni][0], acc[mi][ni][1]),
                                 packbf(acc[mi][ni][2], acc[mi][ni][3])};
              *(uint2v*)(wbase + ni * 4352 + mi * 32) = pw;
            }
        }
        __syncthreads();
        {
          const int col = tt >> 2, s = tt & 3;
          const int C = bn * 256 + hv * 128 + col;
          const int hh2 = (C >> 6) & 15;
          const int dd = C & 63;
          const char* rbase = smem + col * 272 + s * 64;
#pragma unroll
          for (int j = 0; j < 4; ++j) {
            const int R0 = bm * 256 + half * 128 + s * 32 + j * 8;
            if (R0 >= MROWS) continue;
            const int src0 = (R0 >= NTOK) ? 1 : 0;
            const int rr0 = R0 - src0 * NTOK;
            const int bb0 = rr0 / 577;
            const int nn0 = rr0 - bb0 * 577;
            const uint4v v = *(const uint4v*)(rbase + j * 16);
            const uint16_t* pv = (const uint16_t*)&v;
            const bool fast = (R0 + 7 < MROWS) && (nn0 + 8 <= 577) &&
                              (((R0 + 7) >= NTOK ? 1 : 0) == src0);
            if (fast) {
              uint16_t* dst =
                  Vtb + ((((size_t)src0 * 16 + bb0) * 16 + hh2) * 64 + dd) * NPADV + nn0;
#pragma unroll
              for (int e = 0; e < 8; ++e) dst[e] = pv[e];
            } else {
#pragma unroll
              for (int e = 0; e < 8; ++e) {
                const int R = R0 + e;
                if (R >= MROWS) break;
                const int sx = (R >= NTOK) ? 1 : 0;
                const int rr = R - sx * NTOK;
                const int b2 = rr / 577;
                const int n2 = rr - b2 * 577;
                Vtb[((((size_t)sx * 16 + b2) * 16 + hh2) * 64 + dd) * NPADV + n2] = pv[e];
              }
            }
          }
        }
        __syncthreads();
      }
    }
  }
}

// ===== 128x128 tile, BK=32, ring-3, 1-barrier core (proj; R11-verified) ====
#define GEMM_TRI_SETUP                                                         \
  const int srow4 = tt >> 2;      /* 0..63 */                                  \
  const int schunk = tt & 3;      /* 16B chunk in 64B row */                   \
  const int swc = schunk ^ ((srow4 >> 1) & 3);                                 \
  const int crs = (c >> 1) & 3;                                                \
  char* aL = (char*)As3;                                                       \
  char* bL = (char*)Bs3;                                                       \
  auto SA = [&](int buf, int t) {                                              \
    _Pragma("unroll")                                                          \
    for (int i = 0; i < 2; ++i) {                                              \
      const int row = i * 64 + srow4;                                          \
      gl_lds16(aG + (size_t)row * 2048 + t * 64 + (swc << 4),                  \
               aL + buf * 8192 + row * 64 + (schunk << 4));                    \
    }                                                                          \
  };                                                                           \
  auto SB = [&](int buf, int t) {                                              \
    _Pragma("unroll")                                                          \
    for (int i = 0; i < 2; ++i) {                                              \
      const int row = i * 64 + srow4;                                          \
      gl_lds16(bG + (size_t)row * 2048 + t * 64 + (swc << 4),                  \
               bL + buf * 8192 + row * 64 + (schunk << 4));                    \
    }                                                                          \
  };                                                                           \
  auto LDA = [&](int buf, int mi) -> bf16x8 {                                  \
    const int r = wm * 64 + mi * 16 + c;                                       \
    return *(const bf16x8*)(aL + buf * 8192 + r * 64 + ((g ^ crs) << 4));      \
  };                                                                           \
  auto LDB = [&](int buf, int ni) -> bf16x8 {                                  \
    const int r = wn * 64 + ni * 16 + c;                                       \
    return *(const bf16x8*)(bL + buf * 8192 + r * 64 + ((g ^ crs) << 4));      \
  };

#define G_MFMA_BLOCK(BR)                                                       \
  {                                                                            \
    bf16x8 b0 = LDB(BR, 0), b1 = LDB(BR, 1);                                   \
    bf16x8 b2 = LDB(BR, 2), b3 = LDB(BR, 3);                                   \
    __builtin_amdgcn_s_setprio(1);                                             \
    _Pragma("unroll")                                                          \
    for (int mi = 0; mi < 4; ++mi) {                                           \
      const bf16x8 a0 = LDA(BR, mi);                                           \
      acc[mi][0] = mfma16(a0, b0, acc[mi][0]);                                 \
      acc[mi][1] = mfma16(a0, b1, acc[mi][1]);                                 \
      acc[mi][2] = mfma16(a0, b2, acc[mi][2]);                                 \
      acc[mi][3] = mfma16(a0, b3, acc[mi][3]);                                 \
    }                                                                          \
    __builtin_amdgcn_s_setprio(0);                                             \
  }

#define G_ITER_S(T, BR, BS)                                                    \
  {                                                                            \
    asm volatile("s_waitcnt vmcnt(4)" ::: "memory");                           \
    __builtin_amdgcn_s_barrier();                                              \
    __builtin_amdgcn_sched_barrier(0);                                         \
    SA(BS, (T) + 2); SB(BS, (T) + 2);                                          \
    G_MFMA_BLOCK(BR)                                                           \
  }

#define G_ITER_N(BR, VM)                                                       \
  {                                                                            \
    asm volatile("s_waitcnt vmcnt(" #VM ")" ::: "memory");                     \
    __builtin_amdgcn_s_barrier();                                              \
    __builtin_amdgcn_sched_barrier(0);                                         \
    G_MFMA_BLOCK(BR)                                                           \
  }

#define GEMM_TRI_KLOOP                                                         \
  GEMM_TRI_SETUP                                                               \
  SA(0, 0); SB(0, 0); SA(1, 1); SB(1, 1);                                      \
  for (int j = 0; j < 10; ++j) {                                               \
    const int t3 = j * 3;                                                      \
    G_ITER_S(t3, 0, 2)                                                         \
    G_ITER_S(t3 + 1, 1, 0)                                                     \
    G_ITER_S(t3 + 2, 2, 1)                                                     \
  }                                                                            \
  G_ITER_N(0, 4)                                                               \
  G_ITER_N(1, 0)

// ---------------------------------------------------------------- attention
// Cooperative flash attn, 16x16x32 MFMA (R5-verified layouts) + T13
// defer-max (R16-verified) + T5 setprio (R18; isolated this round).
#define KVB 64
#define ATT_NT 10
__global__ __launch_bounds__(256, 2) void attn_kernel(
    const uint16_t* __restrict__ Qb, const uint16_t* __restrict__ Kb,
    const uint16_t* __restrict__ Vtb, uint16_t* __restrict__ O) {
  __shared__ __align__(128) char smem[73728];  // Ks[2][8K] | Vs[2][8K] | P[4][10K]
  const int tid = threadIdx.x;
  const int w = tid >> 6, l = tid & 63;
  const int c = l & 15, g = l >> 4;
  const int bid = blockIdx.x;
  const int qc = bid & 1;
  const int p = bid >> 1;
  const int h = p & 15, b = (p >> 4) & 15, o = p >> 8;
  const int kvsrc = (h < 10) ? o : (1 - o);
  const uint16_t* qp = Qb + (((size_t)o * 16 + b) * 16 + h) * 577 * 64;
  const uint16_t* kp = Kb + (((size_t)kvsrc * 16 + b) * 16 + h) * 577 * 64;
  const uint16_t* vp = Vtb + (((size_t)kvsrc * 16 + b) * 16 + h) * 64 * NPADV;

  const int qbase = qc * 320 + w * 80;

  const int sub = l >> 3;
  const int colEl = (((l & 7) ^ sub) << 3);  // element offset in row
  char* KsA = smem;
  char* VsA = smem + 16384;
  char* Pb  = smem + 32768 + w * 10240;      // per-wave P / epilogue buffer
  const int rs = (c & 7) << 4;               // swizzle for LDS rows ≡ c (mod 8)

  bf16x8 Qf[5][2];
#pragma unroll
  for (int qt = 0; qt < 5; ++qt) {
    const int qrow = min(qbase + qt * 16 + c, 576);
    const uint16_t* qr = qp + (size_t)qrow * 64 + g * 8;
    Qf[qt][0] = *(const bf16x8*)(qr);
    Qf[qt][1] = *(const bf16x8*)(qr + 32);
  }

  f32x4 acc[4][5] = {};  // [dt][qt]
  float m_run[5] = {-3.0e38f, -3.0e38f, -3.0e38f, -3.0e38f, -3.0e38f};
  float l_run[5] = {0.f, 0.f, 0.f, 0.f, 0.f};

  auto STAGE = [&](int buf, int kv0) {
#pragma unroll
    for (int i = 0; i < 2; ++i) {
      const int j = w * 2 + i;
      const int row = j * 8 + sub;
      const int gk = min(kv0 + row, 576);
      gl_lds16(kp + (size_t)gk * 64 + colEl, KsA + buf * 8192 + j * 1024 + l * 16);
      gl_lds16(vp + (size_t)row * NPADV + kv0 + colEl, VsA + buf * 8192 + j * 1024 + l * 16);
    }
  };

  STAGE(0, 0);
  __syncthreads();

  for (int t = 0; t < ATT_NT; ++t) {
    if (t < ATT_NT - 1) STAGE((t + 1) & 1, (t + 1) * KVB);
    {
      const char* Kt = KsA + (t & 1) * 8192;
      const char* Vt = VsA + (t & 1) * 8192;
      bf16x8 Kf[4][2];
#pragma unroll
      for (int kt = 0; kt < 4; ++kt) {
        const char* kr = Kt + (kt * 16 + c) * 128;
        Kf[kt][0] = *(const bf16x8*)(kr + ((g * 16) ^ rs));
        Kf[kt][1] = *(const bf16x8*)(kr + ((64 + g * 16) ^ rs));
      }
      float alpha_[5];
#pragma unroll
      for (int qt = 0; qt < 5; ++qt) {
        f32x4 s[4];
        __builtin_amdgcn_s_setprio(1);
#pragma unroll
        for (int kt = 0; kt < 4; ++kt) {
          f32x4 z = {0.f, 0.f, 0.f, 0.f};
          z = mfma16(Kf[kt][0], Qf[qt][0], z);
          z = mfma16(Kf[kt][1], Qf[qt][1], z);
          s[kt] = z;
        }
        __builtin_amdgcn_s_setprio(0);
        if (t == ATT_NT - 1) {
#pragma unroll
          for (int kt = 0; kt < 4; ++kt)
#pragma unroll
            for (int r = 0; r < 4; ++r) {
              if (kt == 0 && r == 0) { if (g > 0) s[kt][r] = -3.0e38f; }
              else s[kt][r] = -3.0e38f;
            }
        }
        float mt = s[0][0];
#pragma unroll
        for (int kt = 0; kt < 4; ++kt)
#pragma unroll
          for (int r = 0; r < 4; ++r) mt = fmaxf(mt, s[kt][r]);
        mt = fmaxf(mt, __shfl_xor(mt, 16));
        mt = fmaxf(mt, __shfl_xor(mt, 32));
        // T13 defer-max: rescale only when tile max exceeds running max by >8.
        float al;
        if (mt > m_run[qt] + 8.0f) {
          al = exp2f(m_run[qt] - mt);
          m_run[qt] = mt;
        } else {
          al = 1.0f;
        }
        alpha_[qt] = al;
        const float mcur = m_run[qt];
        float lt = 0.f;
#pragma unroll
        for (int kt = 0; kt < 4; ++kt)
#pragma unroll
          for (int r = 0; r < 4; ++r) {
            const float pv = exp2f(s[kt][r] - mcur);
            s[kt][r] = pv;
            lt += pv;
          }
        lt += __shfl_xor(lt, 16);
        lt += __shfl_xor(lt, 32);
        l_run[qt] = l_run[qt] * al + lt;
        const int rowOff = (qt * 16 + c) * 128;
#pragma unroll
        for (int kt = 0; kt < 4; ++kt) {
          const uint2v pw = {packbf(s[kt][0], s[kt][1]), packbf(s[kt][2], s[kt][3])};
          *(uint2v*)(Pb + rowOff + ((kt * 32 + g * 8) ^ rs)) = pw;
        }
      }
#pragma unroll
      for (int qt = 0; qt < 5; ++qt) {
        if (alpha_[qt] != 1.0f) {
#pragma unroll
          for (int dt = 0; dt < 4; ++dt)
#pragma unroll
            for (int r = 0; r < 4; ++r) acc[dt][qt][r] *= alpha_[qt];
        }
      }
      bf16x8 pf[5][2];
#pragma unroll
      for (int qt = 0; qt < 5; ++qt) {
        const char* pr = Pb + (qt * 16 + c) * 128;
        pf[qt][0] = *(const bf16x8*)(pr + ((g * 16) ^ rs));
        pf[qt][1] = *(const bf16x8*)(pr + ((64 + g * 16) ^ rs));
      }
      __builtin_amdgcn_s_setprio(1);
#pragma unroll
      for (int dt = 0; dt < 4; ++dt) {
        const char* vr = Vt + (dt * 16 + c) * 128;
        const bf16x8 v0 = *(const bf16x8*)(vr + ((g * 16) ^ rs));
        const bf16x8 v1 = *(const bf16x8*)(vr + ((64 + g * 16) ^ rs));
#pragma unroll
        for (int qt = 0; qt < 5; ++qt) {
          acc[dt][qt] = mfma16(v0, pf[qt][0], acc[dt][qt]);
          acc[dt][qt] = mfma16(v1, pf[qt][1], acc[dt][qt]);
        }
      }
      __builtin_amdgcn_s_setprio(0);
    }
    __syncthreads();
  }

  {
#pragma unroll
    for (int qt = 0; qt < 5; ++qt) {
      const float inv = 1.0f / l_run[qt];
      const int rowOff = (qt * 16 + c) * 128;
#pragma unroll
      for (int dt = 0; dt < 4; ++dt) {
        const uint2v pw = {packbf(acc[dt][qt][0] * inv, acc[dt][qt][1] * inv),
                           packbf(acc[dt][qt][2] * inv, acc[dt][qt][3] * inv)};
        *(uint2v*)(Pb + rowOff + ((dt * 32 + g * 8) ^ rs)) = pw;
      }
    }
    const size_t obase = ((size_t)o * NTOK + (size_t)b * 577) * 1024 + h * 64;
#pragma unroll
    for (int pass = 0; pass < 10; ++pass) {
      const int row = pass * 8 + (l >> 3);
      const int tok = qbase + row;
      const uint4v vv = *(const uint4v*)(Pb + row * 128 + (((l & 7) * 16) ^ ((row & 7) << 4)));
      if (tok <= 576)
        *(uint4v*)(O + obase + (size_t)tok * 1024 + (l & 7) * 8) = vv;
    }
  }
}

// ---------------------------------------------------------------- Proj GEMM
// 1D grid 1160 = 8 XCD-chunks x 145; raster 6bm x 8bn super-tiles
// (R17-verified 128^2 ring-3 core; 256^2 regressed via 292-block tail, R18).
__global__ __launch_bounds__(256, 3) void gemm_proj_kernel(
    const uint16_t* __restrict__ A, const uint16_t* __restrict__ Bt,
    const float* __restrict__ bias, float* __restrict__ out) {
  __shared__ uint16_t As3[3][4096];
  __shared__ uint16_t Bs3[3][4096];
  const int tt = threadIdx.x;
  const int w = tt >> 6, l = tt & 63;
  const int c = l & 15, g = l >> 4;
  const int wgid = blockIdx.x;
  const int work = (wgid & 7) * 145 + (wgid >> 3);
  int bm, bn;
  {
    const int stripe = work / 48;
    if (stripe >= 24) { bm = 144; bn = work - 24 * 48; }
    else { const int r3 = work % 48; bm = stripe * 6 + r3 % 6; bn = r3 / 6; }
  }
  const int wm = w >> 1, wn = w & 1;
  f32x4 acc[4][4] = {};
  const char* aG = (const char*)(A + (size_t)bm * 128 * 1024);
  const char* bG = (const char*)(Bt + (size_t)bn * 128 * 1024);

  GEMM_TRI_KLOOP

#pragma unroll
  for (int mi = 0; mi < 4; ++mi) {
#pragma unroll
    for (int r = 0; r < 4; ++r) {
      const int R = bm * 128 + wm * 64 + mi * 16 + g * 4 + r;
      if (R >= MROWS) continue;
#pragma unroll
      for (int ni = 0; ni < 4; ++ni) {
        const int C = bn * 128 + wn * 64 + ni * 16 + c;
        out[(size_t)R * 1024 + C] = acc[mi][ni][r] + bias[C];
      }
    }
  }
}

// ---------------------------------------------------------------- launch
extern "C" void kernel_launch(void* const* d_in, const int* in_sizes, int n_in,
                              void* d_out, int out_size, void* d_ws, size_t ws_size,
                              hipStream_t stream) {
  (void)in_sizes; (void)n_in; (void)out_size; (void)ws_size;
  const float* x1    = (const float*)d_in[0];
  const float* x2    = (const float*)d_in[1];
  const float* Wqkv  = (const float*)d_in[2];
  const float* Wproj = (const float*)d_in[3];
  const float* bproj = (const float*)d_in[4];
  float* out = (float*)d_out;

  char* ws = (char*)d_ws;
  size_t off = 0;
  auto alloc = [&](size_t bytes) -> char* {
    char* p = ws + off;
    off += (bytes + 255) & ~(size_t)255;
    return p;
  };
  uint16_t* Xb     = (uint16_t*)alloc((size_t)MPAD * 1024 * 2);      // also AttOut
  uint16_t* Wqkvt  = (uint16_t*)alloc((size_t)3072 * 1024 * 2);
  uint16_t* Wprojt = (uint16_t*)alloc((size_t)1024 * 1024 * 2);
  uint16_t* Qb     = (uint16_t*)alloc((size_t)512 * 577 * 64 * 2);
  uint16_t* Kb     = (uint16_t*)alloc((size_t)512 * 577 * 64 * 2);
  uint16_t* Vtb    = (uint16_t*)alloc((size_t)512 * 64 * NPADV * 2);

  zero_vpad_kernel<<<256, 256, 0, stream>>>(Vtb);
  convert_x_kernel<<<2048, 256, 0, stream>>>(x1, x2, Xb);
  transw_kernel<<<dim3(32, 96), 256, 0, stream>>>(Wqkv, Wqkvt, 1024, 3072);
  transw_kernel<<<dim3(32, 32), 256, 0, stream>>>(Wproj, Wprojt, 1024, 1024);
  gemm_qkv_kernel<<<876, 512, 0, stream>>>(Xb, Wqkvt, Qb, Kb, Vtb);
  attn_kernel<<<1024, 256, 0, stream>>>(Qb, Kb, Vtb, Xb /* AttOut */);
  gemm_proj_kernel<<<1160, 256, 0, stream>>>(Xb, Wprojt, bproj, out);
}

// Round 20
// 347.486 us; speedup vs baseline: 1.0404x; 1.0149x over previous
//
#include <hip/hip_runtime.h>
#include <hip/hip_bf16.h>
#include <stdint.h>
#include <math.h>

typedef __attribute__((ext_vector_type(8))) short bf16x8;
typedef __attribute__((ext_vector_type(4))) float f32x4;
typedef __attribute__((ext_vector_type(8))) unsigned short ushort8;
typedef __attribute__((ext_vector_type(4))) unsigned int uint4v;
typedef __attribute__((ext_vector_type(2))) unsigned int uint2v;

#define NTOK   9232      // 16*577 tokens per stream
#define MROWS  18464     // 2*NTOK
#define MPAD   18688     // 73*256 (also 146*128 for proj tiles)
#define NPADV  640       // padded KV length for Vt rows
// Q prescale: 1/sqrt(64) * log2(e) so softmax uses raw 2^x
#define QSCALE 0.18033688011112042f

__device__ __forceinline__ uint16_t f2b(float f) {
  uint32_t u = __builtin_bit_cast(uint32_t, f);
  u += 0x7fffu + ((u >> 16) & 1u);
  return (uint16_t)(u >> 16);
}

__device__ __forceinline__ uint32_t packbf(float lo, float hi) {
  return (uint32_t)f2b(lo) | ((uint32_t)f2b(hi) << 16);
}

__device__ __forceinline__ f32x4 mfma16(bf16x8 a, bf16x8 b, f32x4 c) {
  return __builtin_amdgcn_mfma_f32_16x16x32_bf16(a, b, c, 0, 0, 0);
}

__device__ __forceinline__ void gl_lds16(const void* g, void* l) {
  __builtin_amdgcn_global_load_lds(
      (const __attribute__((address_space(1))) uint32_t*)g,
      (__attribute__((address_space(3))) uint32_t*)l, 16, 0, 0);
}

// ---------------------------------------------------------------- convert X
__global__ void convert_x_kernel(const float* __restrict__ x1,
                                 const float* __restrict__ x2,
                                 uint16_t* __restrict__ Xb) {
  const size_t stride = (size_t)gridDim.x * blockDim.x;
  const size_t total8 = (size_t)MPAD * 1024 / 8;
  for (size_t i = (size_t)blockIdx.x * blockDim.x + threadIdx.x; i < total8; i += stride) {
    const size_t e = i * 8;
    const size_t row = e >> 10;
    ushort8 ov;
    if (row < (size_t)MROWS) {
      const float* src = (row < (size_t)NTOK) ? (x1 + e) : (x2 + (e - (size_t)NTOK * 1024));
      float4 a = *(const float4*)(src);
      float4 b = *(const float4*)(src + 4);
      ov[0] = f2b(a.x); ov[1] = f2b(a.y); ov[2] = f2b(a.z); ov[3] = f2b(a.w);
      ov[4] = f2b(b.x); ov[5] = f2b(b.y); ov[6] = f2b(b.z); ov[7] = f2b(b.w);
    } else {
      ov = (ushort8)0;
    }
    *(ushort8*)(Xb + e) = ov;
  }
}

// ------------------------------------------------- transpose-convert weights
__global__ void transw_kernel(const float* __restrict__ in, uint16_t* __restrict__ out,
                              int R, int Cc) {
  __shared__ float t[32][33];
  const int r0 = blockIdx.x * 32, c0 = blockIdx.y * 32;
  const int tr = threadIdx.x >> 5, tc = threadIdx.x & 31;
#pragma unroll
  for (int i = 0; i < 4; ++i)
    t[tr + i * 8][tc] = in[(size_t)(r0 + tr + i * 8) * Cc + c0 + tc];
  __syncthreads();
#pragma unroll
  for (int i = 0; i < 4; ++i) {
    const int orow = c0 + tr + i * 8;
    out[(size_t)orow * R + r0 + tc] = f2b(t[tc][tr + i * 8]);
  }
}

// ----------------------------------------------- zero V-pad (replaces memset)
__global__ void zero_vpad_kernel(uint16_t* __restrict__ Vtb) {
  const int idx = blockIdx.x * 256 + threadIdx.x;   // 32768*8 chunks of 16B
  for (int i = idx; i < 32768 * 8; i += 256 * 256) {
    const int p = i >> 3;          // (bh,d) row
    const int ch = i & 7;          // 16B chunk within 128B pad
    *(ushort8*)(Vtb + (size_t)p * NPADV + 576 + ch * 8) = (ushort8)0;
  }
}

// ===== 256x256 tile, BK=32, 8-wave, RING-2, 1-barrier GEMM core ============
// (R17-verified: 64KB LDS, (512,1), 128 VGPR no spill, ~146us on qkv.)
#define G256_SETUP                                                             \
  const int srow = tt >> 2;       /* 0..127 */                                 \
  const int schunk = tt & 3;      /* 16B chunk in 64B row */                   \
  const int swc = schunk ^ ((srow >> 1) & 3);                                  \
  const int crs = (c >> 1) & 3;                                                \
  char* aL = (char*)As3;                                                       \
  char* bL = (char*)Bs3;                                                       \
  auto SA = [&](int buf, int t) {                                              \
    _Pragma("unroll")                                                          \
    for (int i = 0; i < 2; ++i) {                                              \
      const int row = i * 128 + srow;                                          \
      gl_lds16(aG + (size_t)row * 2048 + t * 64 + (swc << 4),                  \
               aL + buf * 16384 + row * 64 + (schunk << 4));                   \
    }                                                                          \
  };                                                                           \
  auto SB = [&](int buf, int t) {                                              \
    _Pragma("unroll")                                                          \
    for (int i = 0; i < 2; ++i) {                                              \
      const int row = i * 128 + srow;                                          \
      gl_lds16(bG + (size_t)row * 2048 + t * 64 + (swc << 4),                  \
               bL + buf * 16384 + row * 64 + (schunk << 4));                   \
    }                                                                          \
  };                                                                           \
  auto LDA = [&](int buf, int mi) -> bf16x8 {                                  \
    const int r = wm * 128 + mi * 16 + c;                                      \
    return *(const bf16x8*)(aL + buf * 16384 + r * 64 + ((g ^ crs) << 4));     \
  };                                                                           \
  auto LDB = [&](int buf, int ni) -> bf16x8 {                                  \
    const int r = wn * 64 + ni * 16 + c;                                       \
    return *(const bf16x8*)(bL + buf * 16384 + r * 64 + ((g ^ crs) << 4));     \
  };

#define G256_MFMA_BLOCK(BR)                                                    \
  {                                                                            \
    bf16x8 b0 = LDB(BR, 0), b1 = LDB(BR, 1);                                   \
    bf16x8 b2 = LDB(BR, 2), b3 = LDB(BR, 3);                                   \
    __builtin_amdgcn_s_setprio(1);                                             \
    _Pragma("unroll")                                                          \
    for (int mi = 0; mi < 8; ++mi) {                                           \
      const bf16x8 a0 = LDA(BR, mi);                                           \
      acc[mi][0] = mfma16(a0, b0, acc[mi][0]);                                 \
      acc[mi][1] = mfma16(a0, b1, acc[mi][1]);                                 \
      acc[mi][2] = mfma16(a0, b2, acc[mi][2]);                                 \
      acc[mi][3] = mfma16(a0, b3, acc[mi][3]);                                 \
    }                                                                          \
    __builtin_amdgcn_s_setprio(0);                                             \
  }

// iter T reading literal buf BR; stage T+1 into BR^1 after the barrier.
#define G256R2_ITER(T, BR)                                                     \
  {                                                                            \
    asm volatile("s_waitcnt vmcnt(0)" ::: "memory");                           \
    __builtin_amdgcn_s_barrier();                                              \
    __builtin_amdgcn_sched_barrier(0);                                         \
    if ((T) < 31) { SA((BR) ^ 1, (T) + 1); SB((BR) ^ 1, (T) + 1); }            \
    G256_MFMA_BLOCK(BR)                                                        \
  }

#define G256_KLOOP                                                             \
  G256_SETUP                                                                   \
  SA(0, 0); SB(0, 0);                                                          \
  for (int j2 = 0; j2 < 16; ++j2) {                                            \
    G256R2_ITER(2 * j2, 0)                                                     \
    G256R2_ITER(2 * j2 + 1, 1)                                                 \
  }

// ---------------------------------------------------------------- QKV GEMM
// grid 876 = 73 bm x 12 bn; bijective XCD swizzle + 3x4 supertile raster.
// Chunked LDS-staged epilogue (R15/R17-verified).
__global__ __launch_bounds__(512, 1) void gemm_qkv_kernel(
    const uint16_t* __restrict__ A, const uint16_t* __restrict__ Bt,
    uint16_t* __restrict__ Qb, uint16_t* __restrict__ Kb, uint16_t* __restrict__ Vtb) {
  __shared__ __align__(128) char smem[65536];
  uint16_t* As3 = (uint16_t*)smem;               // 2 bufs x 16KB
  uint16_t* Bs3 = (uint16_t*)(smem + 32768);     // 2 bufs x 16KB
  const int tt = threadIdx.x;
  const int w = tt >> 6, l = tt & 63;
  const int c = l & 15, g = l >> 4;
  const int wm = w >> 2, wn = w & 3;
  const int orig = blockIdx.x;
  const int xcd = orig & 7, sub8 = orig >> 3;
  const int work = (xcd < 4 ? xcd * 110 : 440 + (xcd - 4) * 109) + sub8;
  int bm, bn;
  {
    const int stripe = work / 36;
    if (stripe >= 24) { bm = 72; bn = work - 864; }
    else {
      const int r2 = work % 36;
      const int bg = r2 / 12, r3 = r2 % 12;
      bm = stripe * 3 + r3 % 3;
      bn = bg * 4 + r3 / 3;
    }
  }
  f32x4 acc[8][4] = {};
  const char* aG = (const char*)(A + (size_t)bm * 256 * 1024);
  const char* bG = (const char*)(Bt + (size_t)bn * 256 * 1024);

  G256_KLOOP

  // ================= LDS-staged epilogue (chunked, R15/R17-verified) =======
  const int sArea = bn >> 2;  // 0:Q 1:K 2:V
  __syncthreads();            // all K-loop LDS reads done; smem reusable
  if (sArea <= 1) {
    uint16_t* outb = (sArea == 0) ? Qb : Kb;
    const float scale = (sArea == 0) ? QSCALE : 1.0f;
#pragma unroll
    for (int q = 0; q < 4; ++q) {
      if (wm == (q >> 1)) {
        char* wbase = smem + (g * 4) * 544 + (wn * 64 + c) * 2;
#pragma unroll
        for (int mi2 = 0; mi2 < 4; ++mi2) {
          const int mi = (q & 1) * 4 + mi2;
#pragma unroll
          for (int r = 0; r < 4; ++r)
#pragma unroll
            for (int ni = 0; ni < 4; ++ni)
              *(uint16_t*)(wbase + mi2 * 8704 + r * 544 + ni * 32) =
                  f2b(acc[mi][ni][r] * scale);
        }
      }
      __syncthreads();
      {
        const int row = tt >> 3, hp = tt & 7;
        const int R = bm * 256 + q * 64 + row;
        if (R < MROWS) {
          const int src = (R >= NTOK) ? 1 : 0;
          const int rr = R - src * NTOK;
          const int bb = rr / 577;
          const int nn = rr - bb * 577;
          const size_t base0 =
              ((((size_t)src * 16 + bb) * 16 + (bn & 3) * 4) * 577 + nn) * 64;
          const char* rbase = smem + row * 544;
#pragma unroll
          for (int j = 0; j < 4; ++j) {
            const int ch = hp + j * 8;
            const int hh2 = ch >> 3;
            const int dd = (ch & 7) * 8;
            const uint4v v = *(const uint4v*)(rbase + ch * 16);
            *(uint4v*)(outb + base0 + (size_t)hh2 * 577 * 64 + dd) = v;
          }
        }
      }
      __syncthreads();
    }
  } else {
#pragma unroll
    for (int half = 0; half < 2; ++half) {
#pragma unroll
      for (int hv = 0; hv < 2; ++hv) {
        if (wm == half && (wn >> 1) == hv) {
          char* wbase = smem + ((wn & 1) * 64 + c) * 272 + g * 8;
#pragma unroll
          for (int mi = 0; mi < 8; ++mi)
#pragma unroll
            for (int ni = 0; ni < 4; ++ni) {
              const uint2v pw = {packbf(acc[mi][ni][0], acc[mi][ni][1]),
                                 packbf(acc[mi][ni][2], acc[mi][ni][3])};
              *(uint2v*)(wbase + ni * 4352 + mi * 32) = pw;
            }
        }
        __syncthreads();
        {
          const int col = tt >> 2, s = tt & 3;
          const int C = bn * 256 + hv * 128 + col;
          const int hh2 = (C >> 6) & 15;
          const int dd = C & 63;
          const char* rbase = smem + col * 272 + s * 64;
#pragma unroll
          for (int j = 0; j < 4; ++j) {
            const int R0 = bm * 256 + half * 128 + s * 32 + j * 8;
            if (R0 >= MROWS) continue;
            const int src0 = (R0 >= NTOK) ? 1 : 0;
            const int rr0 = R0 - src0 * NTOK;
            const int bb0 = rr0 / 577;
            const int nn0 = rr0 - bb0 * 577;
            const uint4v v = *(const uint4v*)(rbase + j * 16);
            const uint16_t* pv = (const uint16_t*)&v;
            const bool fast = (R0 + 7 < MROWS) && (nn0 + 8 <= 577) &&
                              (((R0 + 7) >= NTOK ? 1 : 0) == src0);
            if (fast) {
              uint16_t* dst =
                  Vtb + ((((size_t)src0 * 16 + bb0) * 16 + hh2) * 64 + dd) * NPADV + nn0;
#pragma unroll
              for (int e = 0; e < 8; ++e) dst[e] = pv[e];
            } else {
#pragma unroll
              for (int e = 0; e < 8; ++e) {
                const int R = R0 + e;
                if (R >= MROWS) break;
                const int sx = (R >= NTOK) ? 1 : 0;
                const int rr = R - sx * NTOK;
                const int b2 = rr / 577;
                const int n2 = rr - b2 * 577;
                Vtb[((((size_t)sx * 16 + b2) * 16 + hh2) * 64 + dd) * NPADV + n2] = pv[e];
              }
            }
          }
        }
        __syncthreads();
      }
    }
  }
}

// ===== 128x128 tile, BK=32, ring-3, 1-barrier core (proj; R11-verified) ====
#define GEMM_TRI_SETUP                                                         \
  const int srow4 = tt >> 2;      /* 0..63 */                                  \
  const int schunk = tt & 3;      /* 16B chunk in 64B row */                   \
  const int swc = schunk ^ ((srow4 >> 1) & 3);                                 \
  const int crs = (c >> 1) & 3;                                                \
  char* aL = (char*)As3;                                                       \
  char* bL = (char*)Bs3;                                                       \
  auto SA = [&](int buf, int t) {                                              \
    _Pragma("unroll")                                                          \
    for (int i = 0; i < 2; ++i) {                                              \
      const int row = i * 64 + srow4;                                          \
      gl_lds16(aG + (size_t)row * 2048 + t * 64 + (swc << 4),                  \
               aL + buf * 8192 + row * 64 + (schunk << 4));                    \
    }                                                                          \
  };                                                                           \
  auto SB = [&](int buf, int t) {                                              \
    _Pragma("unroll")                                                          \
    for (int i = 0; i < 2; ++i) {                                              \
      const int row = i * 64 + srow4;                                          \
      gl_lds16(bG + (size_t)row * 2048 + t * 64 + (swc << 4),                  \
               bL + buf * 8192 + row * 64 + (schunk << 4));                    \
    }                                                                          \
  };                                                                           \
  auto LDA = [&](int buf, int mi) -> bf16x8 {                                  \
    const int r = wm * 64 + mi * 16 + c;                                       \
    return *(const bf16x8*)(aL + buf * 8192 + r * 64 + ((g ^ crs) << 4));      \
  };                                                                           \
  auto LDB = [&](int buf, int ni) -> bf16x8 {                                  \
    const int r = wn * 64 + ni * 16 + c;                                       \
    return *(const bf16x8*)(bL + buf * 8192 + r * 64 + ((g ^ crs) << 4));      \
  };

#define G_MFMA_BLOCK(BR)                                                       \
  {                                                                            \
    bf16x8 b0 = LDB(BR, 0), b1 = LDB(BR, 1);                                   \
    bf16x8 b2 = LDB(BR, 2), b3 = LDB(BR, 3);                                   \
    __builtin_amdgcn_s_setprio(1);                                             \
    _Pragma("unroll")                                                          \
    for (int mi = 0; mi < 4; ++mi) {                                           \
      const bf16x8 a0 = LDA(BR, mi);                                           \
      acc[mi][0] = mfma16(a0, b0, acc[mi][0]);                                 \
      acc[mi][1] = mfma16(a0, b1, acc[mi][1]);                                 \
      acc[mi][2] = mfma16(a0, b2, acc[mi][2]);                                 \
      acc[mi][3] = mfma16(a0, b3, acc[mi][3]);                                 \
    }                                                                          \
    __builtin_amdgcn_s_setprio(0);                                             \
  }

#define G_ITER_S(T, BR, BS)                                                    \
  {                                                                            \
    asm volatile("s_waitcnt vmcnt(4)" ::: "memory");                           \
    __builtin_amdgcn_s_barrier();                                              \
    __builtin_amdgcn_sched_barrier(0);                                         \
    SA(BS, (T) + 2); SB(BS, (T) + 2);                                          \
    G_MFMA_BLOCK(BR)                                                           \
  }

#define G_ITER_N(BR, VM)                                                       \
  {                                                                            \
    asm volatile("s_waitcnt vmcnt(" #VM ")" ::: "memory");                     \
    __builtin_amdgcn_s_barrier();                                              \
    __builtin_amdgcn_sched_barrier(0);                                         \
    G_MFMA_BLOCK(BR)                                                           \
  }

#define GEMM_TRI_KLOOP                                                         \
  GEMM_TRI_SETUP                                                               \
  SA(0, 0); SB(0, 0); SA(1, 1); SB(1, 1);                                      \
  for (int j = 0; j < 10; ++j) {                                               \
    const int t3 = j * 3;                                                      \
    G_ITER_S(t3, 0, 2)                                                         \
    G_ITER_S(t3 + 1, 1, 0)                                                     \
    G_ITER_S(t3 + 2, 2, 1)                                                     \
  }                                                                            \
  G_ITER_N(0, 4)                                                               \
  G_ITER_N(1, 0)

// ---------------------------------------------------------------- attention
// Cooperative flash attn, 16x16x32 MFMA (R5-verified layouts) + T13
// defer-max (R16-verified). NO setprio: R19 A/B showed it costs ~4us on
// this barrier-lockstep 4-wave structure (m190-consistent).
#define KVB 64
#define ATT_NT 10
__global__ __launch_bounds__(256, 2) void attn_kernel(
    const uint16_t* __restrict__ Qb, const uint16_t* __restrict__ Kb,
    const uint16_t* __restrict__ Vtb, uint16_t* __restrict__ O) {
  __shared__ __align__(128) char smem[73728];  // Ks[2][8K] | Vs[2][8K] | P[4][10K]
  const int tid = threadIdx.x;
  const int w = tid >> 6, l = tid & 63;
  const int c = l & 15, g = l >> 4;
  const int bid = blockIdx.x;
  const int qc = bid & 1;
  const int p = bid >> 1;
  const int h = p & 15, b = (p >> 4) & 15, o = p >> 8;
  const int kvsrc = (h < 10) ? o : (1 - o);
  const uint16_t* qp = Qb + (((size_t)o * 16 + b) * 16 + h) * 577 * 64;
  const uint16_t* kp = Kb + (((size_t)kvsrc * 16 + b) * 16 + h) * 577 * 64;
  const uint16_t* vp = Vtb + (((size_t)kvsrc * 16 + b) * 16 + h) * 64 * NPADV;

  const int qbase = qc * 320 + w * 80;

  const int sub = l >> 3;
  const int colEl = (((l & 7) ^ sub) << 3);  // element offset in row
  char* KsA = smem;
  char* VsA = smem + 16384;
  char* Pb  = smem + 32768 + w * 10240;      // per-wave P / epilogue buffer
  const int rs = (c & 7) << 4;               // swizzle for LDS rows ≡ c (mod 8)

  bf16x8 Qf[5][2];
#pragma unroll
  for (int qt = 0; qt < 5; ++qt) {
    const int qrow = min(qbase + qt * 16 + c, 576);
    const uint16_t* qr = qp + (size_t)qrow * 64 + g * 8;
    Qf[qt][0] = *(const bf16x8*)(qr);
    Qf[qt][1] = *(const bf16x8*)(qr + 32);
  }

  f32x4 acc[4][5] = {};  // [dt][qt]
  float m_run[5] = {-3.0e38f, -3.0e38f, -3.0e38f, -3.0e38f, -3.0e38f};
  float l_run[5] = {0.f, 0.f, 0.f, 0.f, 0.f};

  auto STAGE = [&](int buf, int kv0) {
#pragma unroll
    for (int i = 0; i < 2; ++i) {
      const int j = w * 2 + i;
      const int row = j * 8 + sub;
      const int gk = min(kv0 + row, 576);
      gl_lds16(kp + (size_t)gk * 64 + colEl, KsA + buf * 8192 + j * 1024 + l * 16);
      gl_lds16(vp + (size_t)row * NPADV + kv0 + colEl, VsA + buf * 8192 + j * 1024 + l * 16);
    }
  };

  STAGE(0, 0);
  __syncthreads();

  for (int t = 0; t < ATT_NT; ++t) {
    if (t < ATT_NT - 1) STAGE((t + 1) & 1, (t + 1) * KVB);
    {
      const char* Kt = KsA + (t & 1) * 8192;
      const char* Vt = VsA + (t & 1) * 8192;
      bf16x8 Kf[4][2];
#pragma unroll
      for (int kt = 0; kt < 4; ++kt) {
        const char* kr = Kt + (kt * 16 + c) * 128;
        Kf[kt][0] = *(const bf16x8*)(kr + ((g * 16) ^ rs));
        Kf[kt][1] = *(const bf16x8*)(kr + ((64 + g * 16) ^ rs));
      }
      float alpha_[5];
#pragma unroll
      for (int qt = 0; qt < 5; ++qt) {
        f32x4 s[4];
#pragma unroll
        for (int kt = 0; kt < 4; ++kt) {
          f32x4 z = {0.f, 0.f, 0.f, 0.f};
          z = mfma16(Kf[kt][0], Qf[qt][0], z);
          z = mfma16(Kf[kt][1], Qf[qt][1], z);
          s[kt] = z;
        }
        if (t == ATT_NT - 1) {
#pragma unroll
          for (int kt = 0; kt < 4; ++kt)
#pragma unroll
            for (int r = 0; r < 4; ++r) {
              if (kt == 0 && r == 0) { if (g > 0) s[kt][r] = -3.0e38f; }
              else s[kt][r] = -3.0e38f;
            }
        }
        float mt = s[0][0];
#pragma unroll
        for (int kt = 0; kt < 4; ++kt)
#pragma unroll
          for (int r = 0; r < 4; ++r) mt = fmaxf(mt, s[kt][r]);
        mt = fmaxf(mt, __shfl_xor(mt, 16));
        mt = fmaxf(mt, __shfl_xor(mt, 32));
        // T13 defer-max: rescale only when tile max exceeds running max by >8.
        float al;
        if (mt > m_run[qt] + 8.0f) {
          al = exp2f(m_run[qt] - mt);
          m_run[qt] = mt;
        } else {
          al = 1.0f;
        }
        alpha_[qt] = al;
        const float mcur = m_run[qt];
        float lt = 0.f;
#pragma unroll
        for (int kt = 0; kt < 4; ++kt)
#pragma unroll
          for (int r = 0; r < 4; ++r) {
            const float pv = exp2f(s[kt][r] - mcur);
            s[kt][r] = pv;
            lt += pv;
          }
        lt += __shfl_xor(lt, 16);
        lt += __shfl_xor(lt, 32);
        l_run[qt] = l_run[qt] * al + lt;
        const int rowOff = (qt * 16 + c) * 128;
#pragma unroll
        for (int kt = 0; kt < 4; ++kt) {
          const uint2v pw = {packbf(s[kt][0], s[kt][1]), packbf(s[kt][2], s[kt][3])};
          *(uint2v*)(Pb + rowOff + ((kt * 32 + g * 8) ^ rs)) = pw;
        }
      }
#pragma unroll
      for (int qt = 0; qt < 5; ++qt) {
        if (alpha_[qt] != 1.0f) {
#pragma unroll
          for (int dt = 0; dt < 4; ++dt)
#pragma unroll
            for (int r = 0; r < 4; ++r) acc[dt][qt][r] *= alpha_[qt];
        }
      }
      bf16x8 pf[5][2];
#pragma unroll
      for (int qt = 0; qt < 5; ++qt) {
        const char* pr = Pb + (qt * 16 + c) * 128;
        pf[qt][0] = *(const bf16x8*)(pr + ((g * 16) ^ rs));
        pf[qt][1] = *(const bf16x8*)(pr + ((64 + g * 16) ^ rs));
      }
#pragma unroll
      for (int dt = 0; dt < 4; ++dt) {
        const char* vr = Vt + (dt * 16 + c) * 128;
        const bf16x8 v0 = *(const bf16x8*)(vr + ((g * 16) ^ rs));
        const bf16x8 v1 = *(const bf16x8*)(vr + ((64 + g * 16) ^ rs));
#pragma unroll
        for (int qt = 0; qt < 5; ++qt) {
          acc[dt][qt] = mfma16(v0, pf[qt][0], acc[dt][qt]);
          acc[dt][qt] = mfma16(v1, pf[qt][1], acc[dt][qt]);
        }
      }
    }
    __syncthreads();
  }

  {
#pragma unroll
    for (int qt = 0; qt < 5; ++qt) {
      const float inv = 1.0f / l_run[qt];
      const int rowOff = (qt * 16 + c) * 128;
#pragma unroll
      for (int dt = 0; dt < 4; ++dt) {
        const uint2v pw = {packbf(acc[dt][qt][0] * inv, acc[dt][qt][1] * inv),
                           packbf(acc[dt][qt][2] * inv, acc[dt][qt][3] * inv)};
        *(uint2v*)(Pb + rowOff + ((dt * 32 + g * 8) ^ rs)) = pw;
      }
    }
    const size_t obase = ((size_t)o * NTOK + (size_t)b * 577) * 1024 + h * 64;
#pragma unroll
    for (int pass = 0; pass < 10; ++pass) {
      const int row = pass * 8 + (l >> 3);
      const int tok = qbase + row;
      const uint4v vv = *(const uint4v*)(Pb + row * 128 + (((l & 7) * 16) ^ ((row & 7) << 4)));
      if (tok <= 576)
        *(uint4v*)(O + obase + (size_t)tok * 1024 + (l & 7) * 8) = vv;
    }
  }
}

// ---------------------------------------------------------------- Proj GEMM
// 1D grid 1160 = 8 XCD-chunks x 145; raster 6bm x 8bn super-tiles
// (R17-verified 128^2 ring-3 core; 256^2 regressed via 292-block tail, R18).
__global__ __launch_bounds__(256, 3) void gemm_proj_kernel(
    const uint16_t* __restrict__ A, const uint16_t* __restrict__ Bt,
    const float* __restrict__ bias, float* __restrict__ out) {
  __shared__ uint16_t As3[3][4096];
  __shared__ uint16_t Bs3[3][4096];
  const int tt = threadIdx.x;
  const int w = tt >> 6, l = tt & 63;
  const int c = l & 15, g = l >> 4;
  const int wgid = blockIdx.x;
  const int work = (wgid & 7) * 145 + (wgid >> 3);
  int bm, bn;
  {
    const int stripe = work / 48;
    if (stripe >= 24) { bm = 144; bn = work - 24 * 48; }
    else { const int r3 = work % 48; bm = stripe * 6 + r3 % 6; bn = r3 / 6; }
  }
  const int wm = w >> 1, wn = w & 1;
  f32x4 acc[4][4] = {};
  const char* aG = (const char*)(A + (size_t)bm * 128 * 1024);
  const char* bG = (const char*)(Bt + (size_t)bn * 128 * 1024);

  GEMM_TRI_KLOOP

#pragma unroll
  for (int mi = 0; mi < 4; ++mi) {
#pragma unroll
    for (int r = 0; r < 4; ++r) {
      const int R = bm * 128 + wm * 64 + mi * 16 + g * 4 + r;
      if (R >= MROWS) continue;
#pragma unroll
      for (int ni = 0; ni < 4; ++ni) {
        const int C = bn * 128 + wn * 64 + ni * 16 + c;
        out[(size_t)R * 1024 + C] = acc[mi][ni][r] + bias[C];
      }
    }
  }
}

// ---------------------------------------------------------------- launch
extern "C" void kernel_launch(void* const* d_in, const int* in_sizes, int n_in,
                              void* d_out, int out_size, void* d_ws, size_t ws_size,
                              hipStream_t stream) {
  (void)in_sizes; (void)n_in; (void)out_size; (void)ws_size;
  const float* x1    = (const float*)d_in[0];
  const float* x2    = (const float*)d_in[1];
  const float* Wqkv  = (const float*)d_in[2];
  const float* Wproj = (const float*)d_in[3];
  const float* bproj = (const float*)d_in[4];
  float* out = (float*)d_out;

  char* ws = (char*)d_ws;
  size_t off = 0;
  auto alloc = [&](size_t bytes) -> char* {
    char* p = ws + off;
    off += (bytes + 255) & ~(size_t)255;
    return p;
  };
  uint16_t* Xb     = (uint16_t*)alloc((size_t)MPAD * 1024 * 2);      // also AttOut
  uint16_t* Wqkvt  = (uint16_t*)alloc((size_t)3072 * 1024 * 2);
  uint16_t* Wprojt = (uint16_t*)alloc((size_t)1024 * 1024 * 2);
  uint16_t* Qb     = (uint16_t*)alloc((size_t)512 * 577 * 64 * 2);
  uint16_t* Kb     = (uint16_t*)alloc((size_t)512 * 577 * 64 * 2);
  uint16_t* Vtb    = (uint16_t*)alloc((size_t)512 * 64 * NPADV * 2);

  zero_vpad_kernel<<<256, 256, 0, stream>>>(Vtb);
  convert_x_kernel<<<2048, 256, 0, stream>>>(x1, x2, Xb);
  transw_kernel<<<dim3(32, 96), 256, 0, stream>>>(Wqkv, Wqkvt, 1024, 3072);
  transw_kernel<<<dim3(32, 32), 256, 0, stream>>>(Wproj, Wprojt, 1024, 1024);
  gemm_qkv_kernel<<<876, 512, 0, stream>>>(Xb, Wqkvt, Qb, Kb, Vtb);
  attn_kernel<<<1024, 256, 0, stream>>>(Qb, Kb, Vtb, Xb /* AttOut */);
  gemm_proj_kernel<<<1160, 256, 0, stream>>>(Xb, Wprojt, bproj, out);
}